// Round 2
// baseline (254.513 us; speedup 1.0000x reference)
//
#include <hip/hip_runtime.h>

#define BATCH 2048
#define SIZE 4096
#define DOWN 256
#define NTASK 16
#define KC 16
#define KCHUNK (SIZE / KC)  // 256

typedef _Float16 half8 __attribute__((ext_vector_type(8)));
typedef _Float16 half4 __attribute__((ext_vector_type(4)));
typedef float floatx4 __attribute__((ext_vector_type(4)));

__device__ __forceinline__ int imin(int a, int b) { return a < b ? a : b; }

// ---------------- counting sort: group samples by task ----------------
__global__ __launch_bounds__(256) void sort_kernel(const int* __restrict__ task_id,
                                                   int* __restrict__ taskOff,
                                                   int* __restrict__ sortedIdx,
                                                   int* __restrict__ taskOfPos) {
    __shared__ int cnt[NTASK];
    __shared__ int base[NTASK + 1];
    __shared__ int cur[NTASK];
    int tid = threadIdx.x;
    if (tid < NTASK) cnt[tid] = 0;
    __syncthreads();
    for (int i = tid; i < BATCH; i += 256) atomicAdd(&cnt[task_id[i]], 1);
    __syncthreads();
    if (tid == 0) {
        int s = 0;
        for (int t = 0; t < NTASK; t++) { base[t] = s; s += cnt[t]; }
        base[NTASK] = s;
    }
    __syncthreads();
    if (tid < NTASK) { cur[tid] = base[tid]; taskOff[tid] = base[tid]; }
    if (tid == 0) taskOff[NTASK] = BATCH;
    __syncthreads();
    for (int i = tid; i < BATCH; i += 256) {
        int t = task_id[i];
        int p = atomicAdd(&cur[t], 1);
        sortedIdx[p] = i;
        taskOfPos[p] = t;
    }
}

// ---------------- GEMM1: partial[kc][s][h] = x[rows(t)] @ Wd[t] (K-chunked) ----
// Wave-autonomous streaming: NO barriers in the K loop. A (shared across waves)
// is staged once per row-tile for the whole K-chunk (2 barriers / 4 ksteps).
// B (zero cross-wave reuse) is staged into a wave-PRIVATE LDS region; within a
// wave the in-order DS pipe + compiler lgkmcnt make write->read safe without
// __syncthreads. Waves free-run => HBM queue never drains (kills the convoy).
__global__ __launch_bounds__(256, 2) void gemm1_kernel(const float* __restrict__ x,
                                                       const float* __restrict__ Wd,
                                                       const int* __restrict__ taskOff,
                                                       const int* __restrict__ sortedIdx,
                                                       _Float16* __restrict__ partial) {
    int task = blockIdx.x >> 1, z = blockIdx.x & 1, kc = blockIdx.y;
    int rowStart = taskOff[task];
    int nrows = taskOff[task + 1] - rowStart;
    if (nrows <= 0) return;

    __shared__ half8 A_lds[32][64];    // [kg over KCHUNK=256][row]      32 KB
    __shared__ half8 B_lds[4][64][8];  // [wave][n][kg within kstep]     32 KB

    int tid = threadIdx.x;
    int wave = tid >> 6, lane = tid & 63, quad = lane >> 4, l15 = lane & 15;
    int kbase = kc * KCHUNK;
    const float* Wdt = Wd + (size_t)task * SIZE * DOWN;
    int arow = tid >> 2, ac = tid & 3;

    for (int r0 = z * 64; r0 < nrows; r0 += 128) {
        __syncthreads();  // all waves done reading previous A tile
        {
            // stage A rows r0..r0+63, k = kbase..kbase+255 (fp32 -> fp16)
            int asrc = sortedIdx[rowStart + imin(r0 + arow, nrows - 1)];
            const float* xr = x + (size_t)asrc * SIZE + kbase;
            floatx4 f[16];
#pragma unroll
            for (int i = 0; i < 16; i++)  // 4 lanes cover 64B contiguous per row
                f[i] = *(const floatx4*)(xr + i * 16 + ac * 4);
#pragma unroll
            for (int i = 0; i < 16; i++) {
                half4 h;
                h[0] = (_Float16)f[i][0]; h[1] = (_Float16)f[i][1];
                h[2] = (_Float16)f[i][2]; h[3] = (_Float16)f[i][3];
                int kg = i * 2 + (ac >> 1);
                *((half4*)(&A_lds[kg][arow]) + (ac & 1)) = h;
            }
        }
        __syncthreads();

        floatx4 acc[4][4];
#pragma unroll
        for (int mi = 0; mi < 4; mi++)
#pragma unroll
            for (int ni = 0; ni < 4; ni++) acc[mi][ni] = (floatx4){0.f, 0.f, 0.f, 0.f};

        for (int kb = 0; kb < KCHUNK; kb += 64) {
            // wave-private B strip: 64k x 64n. lane = (quad: 16-consecutive-k
            // group, l15: float4 col). Per instr: 4 rows x 256B contiguous.
            floatx4 fb[16];
            const float* bs =
                Wdt + (size_t)(kbase + kb + quad * 16) * DOWN + wave * 64 + l15 * 4;
#pragma unroll
            for (int j = 0; j < 16; j++) fb[j] = *(const floatx4*)(bs + (size_t)j * DOWN);
            // pack k-major half8 per n (lane holds 16 consecutive k x 4 n)
#pragma unroll
            for (int g = 0; g < 2; g++)
#pragma unroll
                for (int n2 = 0; n2 < 4; n2++) {
                    half8 h;
#pragma unroll
                    for (int e = 0; e < 8; e++) h[e] = (_Float16)fb[g * 8 + e][n2];
                    B_lds[wave][l15 * 4 + n2][quad * 2 + g] = h;
                }
            // MFMA (same-wave ds write->read: in-order DS pipe, lgkmcnt only)
#pragma unroll
            for (int ks = 0; ks < 2; ks++) {
                int kg = (kb >> 3) + ks * 4 + quad;
                half8 a[4], b[4];
#pragma unroll
                for (int i = 0; i < 4; i++) a[i] = A_lds[kg][i * 16 + l15];
#pragma unroll
                for (int i = 0; i < 4; i++) b[i] = B_lds[wave][i * 16 + l15][ks * 4 + quad];
#pragma unroll
                for (int mi = 0; mi < 4; mi++)
#pragma unroll
                    for (int ni = 0; ni < 4; ni++)
                        acc[mi][ni] = __builtin_amdgcn_mfma_f32_16x16x32_f16(
                            a[mi], b[ni], acc[mi][ni], 0, 0, 0);
            }
        }
        // epilogue: partial[kc][rowStart+r][h], fp16
#pragma unroll
        for (int mi = 0; mi < 4; mi++) {
#pragma unroll
            for (int reg = 0; reg < 4; reg++) {
                int r = r0 + mi * 16 + quad * 4 + reg;
                if (r < nrows) {
                    size_t rowoff = ((size_t)kc * BATCH + (rowStart + r)) * DOWN;
#pragma unroll
                    for (int ni = 0; ni < 4; ni++) {
                        int h = wave * 64 + ni * 16 + l15;
                        partial[rowoff + h] = (_Float16)acc[mi][ni][reg];
                    }
                }
            }
        }
    }
}

// ---------------- SiLU: act[s][h] = silu(sum_kc partial + bd), half8-vectorized --
__global__ __launch_bounds__(256) void silu_kernel(const _Float16* __restrict__ partial,
                                                   const float* __restrict__ bd,
                                                   const int* __restrict__ taskOfPos,
                                                   _Float16* __restrict__ act) {
    int idx = blockIdx.x * 256 + threadIdx.x;  // BATCH*DOWN/8 = 65536 total
    int s = idx >> 5;                          // 32 half8 chunks per row
    int h = (idx & 31) * 8;
    int t = taskOfPos[s];
    floatx4 b0 = *(const floatx4*)(bd + t * DOWN + h);
    floatx4 b1 = *(const floatx4*)(bd + t * DOWN + h + 4);
    float v[8];
    v[0] = b0[0]; v[1] = b0[1]; v[2] = b0[2]; v[3] = b0[3];
    v[4] = b1[0]; v[5] = b1[1]; v[6] = b1[2]; v[7] = b1[3];
#pragma unroll
    for (int kc = 0; kc < KC; kc++) {
        half8 p = *(const half8*)(partial + ((size_t)kc * BATCH + s) * DOWN + h);
#pragma unroll
        for (int j = 0; j < 8; j++) v[j] += (float)p[j];
    }
    half8 o;
#pragma unroll
    for (int j = 0; j < 8; j++) {
        float sv = v[j] / (1.0f + __expf(-v[j]));
        o[j] = (_Float16)sv;
    }
    *(half8*)(act + (size_t)s * DOWN + h) = o;
}

// ---------------- GEMM2: out = x + act @ Wu[t] + bu ----------------
// Same wave-autonomous skeleton: block tile M=64 x N=256 (wave n-strip 64),
// K = DOWN = 256 staged whole for A, B wave-private per BK=64 kstep.
__global__ __launch_bounds__(256, 2) void gemm2_kernel(const _Float16* __restrict__ act,
                                                       const float* __restrict__ Wu,
                                                       const float* __restrict__ bu,
                                                       const float* __restrict__ x,
                                                       const int* __restrict__ taskOff,
                                                       const int* __restrict__ sortedIdx,
                                                       float* __restrict__ out) {
    int nt = blockIdx.x >> 1, z = blockIdx.x & 1, task = blockIdx.y;
    int rowStart = taskOff[task];
    int nrows = taskOff[task + 1] - rowStart;
    if (nrows <= 0) return;

    __shared__ half8 A_lds[32][64];    // [kg over K=256][row]        32 KB
    __shared__ half8 B_lds[4][64][8];  // [wave][n][kg within kstep]  32 KB

    int tid = threadIdx.x;
    int wave = tid >> 6, lane = tid & 63, quad = lane >> 4, l15 = lane & 15;
    int ncol0 = nt * 256;
    const float* Wut = Wu + (size_t)task * DOWN * SIZE;
    int arow = tid >> 2, ac = tid & 3;

    for (int r0 = z * 64; r0 < nrows; r0 += 128) {
        __syncthreads();
        {
            // stage A (act rows, already fp16): per instr 4 lanes x 16B = 64B/row
            int s_a = rowStart + imin(r0 + arow, nrows - 1);
            const _Float16* ar = act + (size_t)s_a * DOWN;
#pragma unroll
            for (int j = 0; j < 8; j++) {
                int kg = j * 4 + ac;
                A_lds[kg][arow] = *(const half8*)(ar + kg * 8);
            }
        }
        __syncthreads();

        floatx4 acc[4][4];
#pragma unroll
        for (int mi = 0; mi < 4; mi++)
#pragma unroll
            for (int ni = 0; ni < 4; ni++) acc[mi][ni] = (floatx4){0.f, 0.f, 0.f, 0.f};

        for (int kb = 0; kb < DOWN; kb += 64) {
            floatx4 fb[16];
            const float* bs =
                Wut + (size_t)(kb + quad * 16) * SIZE + ncol0 + wave * 64 + l15 * 4;
#pragma unroll
            for (int j = 0; j < 16; j++) fb[j] = *(const floatx4*)(bs + (size_t)j * SIZE);
#pragma unroll
            for (int g = 0; g < 2; g++)
#pragma unroll
                for (int n2 = 0; n2 < 4; n2++) {
                    half8 h;
#pragma unroll
                    for (int e = 0; e < 8; e++) h[e] = (_Float16)fb[g * 8 + e][n2];
                    B_lds[wave][l15 * 4 + n2][quad * 2 + g] = h;
                }
#pragma unroll
            for (int ks = 0; ks < 2; ks++) {
                int kg = (kb >> 3) + ks * 4 + quad;
                half8 a[4], b[4];
#pragma unroll
                for (int i = 0; i < 4; i++) a[i] = A_lds[kg][i * 16 + l15];
#pragma unroll
                for (int i = 0; i < 4; i++) b[i] = B_lds[wave][i * 16 + l15][ks * 4 + quad];
#pragma unroll
                for (int mi = 0; mi < 4; mi++)
#pragma unroll
                    for (int ni = 0; ni < 4; ni++)
                        acc[mi][ni] = __builtin_amdgcn_mfma_f32_16x16x32_f16(
                            a[mi], b[ni], acc[mi][ni], 0, 0, 0);
            }
        }
        // epilogue: scatter to original rows, add bias + fp32 residual
#pragma unroll
        for (int mi = 0; mi < 4; mi++) {
#pragma unroll
            for (int reg = 0; reg < 4; reg++) {
                int r = r0 + mi * 16 + quad * 4 + reg;
                if (r < nrows) {
                    int b = sortedIdx[rowStart + r];
                    const float* xr = x + (size_t)b * SIZE;
                    float* outr = out + (size_t)b * SIZE;
#pragma unroll
                    for (int ni = 0; ni < 4; ni++) {
                        int n = ncol0 + wave * 64 + ni * 16 + l15;
                        outr[n] = acc[mi][ni][reg] + bu[task * SIZE + n] + xr[n];
                    }
                }
            }
        }
    }
}

extern "C" void kernel_launch(void* const* d_in, const int* in_sizes, int n_in,
                              void* d_out, int out_size, void* d_ws, size_t ws_size,
                              hipStream_t stream) {
    const float* x       = (const float*)d_in[0];
    const int*   task_id = (const int*)d_in[1];
    const float* Wd      = (const float*)d_in[2];
    const float* bd      = (const float*)d_in[3];
    const float* Wu      = (const float*)d_in[4];
    const float* bu      = (const float*)d_in[5];
    float* out = (float*)d_out;

    // partial (16 MB) lives in d_out: it is dead before gemm2 launches, and
    // gemm2 overwrites every byte of d_out. act + index arrays live in d_ws.
    _Float16* partial = (_Float16*)d_out;               // KC*BATCH*DOWN fp16 = 16 MB
    _Float16* act     = (_Float16*)d_ws;                // BATCH*DOWN fp16 = 1 MB
    int* taskOff   = (int*)(act + (size_t)BATCH * DOWN);
    int* sortedIdx = taskOff + 32;
    int* taskOfPos = sortedIdx + BATCH;

    sort_kernel<<<1, 256, 0, stream>>>(task_id, taskOff, sortedIdx, taskOfPos);
    gemm1_kernel<<<dim3(NTASK * 2, KC), 256, 0, stream>>>(x, Wd, taskOff, sortedIdx, partial);
    silu_kernel<<<(BATCH * DOWN / 8) / 256, 256, 0, stream>>>(partial, bd, taskOfPos, act);
    gemm2_kernel<<<dim3(32, NTASK), 256, 0, stream>>>(act, Wu, bu, x, taskOff,
                                                      sortedIdx, out);
}